// Round 1
// baseline (486.392 us; speedup 1.0000x reference)
//
#include <hip/hip_runtime.h>

typedef __attribute__((ext_vector_type(8))) short bf16x8;
typedef __attribute__((ext_vector_type(4))) float f32x4;

#define NB 8
#define NC 192
#define NO 576
#define NHW 16384
#define NH 6

__device__ __forceinline__ float bf2f(unsigned short u){
  return __uint_as_float(((unsigned int)u) << 16);
}
__device__ __forceinline__ unsigned short f2bf(float f){
  unsigned int u = __float_as_uint(f);
  u += 0x7FFFu + ((u >> 16) & 1u);   // RNE
  return (unsigned short)(u >> 16);
}

template<typename T> __device__ __forceinline__ float4 ld4(const T* p);
template<> __device__ __forceinline__ float4 ld4<float>(const float* p){
  return *(const float4*)p;
}
template<> __device__ __forceinline__ float4 ld4<unsigned short>(const unsigned short* p){
  ushort4 u = *(const ushort4*)p;
  return make_float4(bf2f(u.x), bf2f(u.y), bf2f(u.z), bf2f(u.w));
}

__device__ __forceinline__ void st1(unsigned short* p, float v){ *p = f2bf(v); }
__device__ __forceinline__ void st1(float* p, float v){ *p = v; }

#define LSTR 200   // LDS row stride in ushorts: 192 + 8 pad -> 400 B rows, 2-way conflict (free)

// out[b][o][n] = sum_c A[b?][o][c] * B[b][c][n],  K=192, N=16384, o tiled by 64.
// X tile staged once per block (transposed, bf16); o-tiles looped inside block.
template<typename AT, typename BT, typename OT>
__global__ __launch_bounds__(256) void gemm192(
    const AT* __restrict__ A, long long a_bstride, int o_tiles,
    const BT* __restrict__ Bm, long long b_bstride,
    OT* __restrict__ Out, long long o_bstride)
{
  __shared__ __align__(16) unsigned short Wt[64 * LSTR];
  __shared__ __align__(16) unsigned short Xt[128 * LSTR];
  const int t  = threadIdx.x;
  const int b  = blockIdx.z;
  const int n0 = blockIdx.x * 128;
  const AT* Ab = A  + a_bstride * b;
  const BT* Bb = Bm + b_bstride * b;

  // stage X tile transposed: Xt[n][c]
  for (int idx = t; idx < 1536; idx += 256){
    const int n4 = (idx & 31) * 4;
    const int c  = (idx >> 5) * 4;
    float4 f0 = ld4(Bb + (long long)(c+0)*NHW + n0 + n4);
    float4 f1 = ld4(Bb + (long long)(c+1)*NHW + n0 + n4);
    float4 f2 = ld4(Bb + (long long)(c+2)*NHW + n0 + n4);
    float4 f3 = ld4(Bb + (long long)(c+3)*NHW + n0 + n4);
    *(ushort4*)&Xt[(n4+0)*LSTR + c] = make_ushort4(f2bf(f0.x), f2bf(f1.x), f2bf(f2.x), f2bf(f3.x));
    *(ushort4*)&Xt[(n4+1)*LSTR + c] = make_ushort4(f2bf(f0.y), f2bf(f1.y), f2bf(f2.y), f2bf(f3.y));
    *(ushort4*)&Xt[(n4+2)*LSTR + c] = make_ushort4(f2bf(f0.z), f2bf(f1.z), f2bf(f2.z), f2bf(f3.z));
    *(ushort4*)&Xt[(n4+3)*LSTR + c] = make_ushort4(f2bf(f0.w), f2bf(f1.w), f2bf(f2.w), f2bf(f3.w));
  }
  __syncthreads();

  const int l  = t & 63;
  const int w  = t >> 6;
  const int wo = (w >> 1) * 32;
  const int wn = (w & 1) * 64;
  const int lr = l & 15;
  const int lg = l >> 4;

  for (int ot = 0; ot < o_tiles; ++ot){
    const int o0 = ot * 64;
    for (int idx = t; idx < 3072; idx += 256){
      const int row = idx / 48;
      const int c4  = (idx % 48) * 4;
      float4 f = ld4(Ab + (long long)(o0 + row)*NC + c4);
      *(ushort4*)&Wt[row*LSTR + c4] = make_ushort4(f2bf(f.x), f2bf(f.y), f2bf(f.z), f2bf(f.w));
    }
    __syncthreads();

    f32x4 acc[2][4];
    #pragma unroll
    for (int i=0;i<2;i++)
      #pragma unroll
      for (int j=0;j<4;j++) acc[i][j] = (f32x4){0.f,0.f,0.f,0.f};

    #pragma unroll
    for (int k = 0; k < 192; k += 32){
      const int kc = k + lg*8;
      bf16x8 a0 = *(const bf16x8*)&Wt[(wo +      lr)*LSTR + kc];
      bf16x8 a1 = *(const bf16x8*)&Wt[(wo + 16 + lr)*LSTR + kc];
      bf16x8 b0 = *(const bf16x8*)&Xt[(wn +      lr)*LSTR + kc];
      bf16x8 b1 = *(const bf16x8*)&Xt[(wn + 16 + lr)*LSTR + kc];
      bf16x8 b2 = *(const bf16x8*)&Xt[(wn + 32 + lr)*LSTR + kc];
      bf16x8 b3 = *(const bf16x8*)&Xt[(wn + 48 + lr)*LSTR + kc];
      acc[0][0] = __builtin_amdgcn_mfma_f32_16x16x32_bf16(a0, b0, acc[0][0], 0,0,0);
      acc[0][1] = __builtin_amdgcn_mfma_f32_16x16x32_bf16(a0, b1, acc[0][1], 0,0,0);
      acc[0][2] = __builtin_amdgcn_mfma_f32_16x16x32_bf16(a0, b2, acc[0][2], 0,0,0);
      acc[0][3] = __builtin_amdgcn_mfma_f32_16x16x32_bf16(a0, b3, acc[0][3], 0,0,0);
      acc[1][0] = __builtin_amdgcn_mfma_f32_16x16x32_bf16(a1, b0, acc[1][0], 0,0,0);
      acc[1][1] = __builtin_amdgcn_mfma_f32_16x16x32_bf16(a1, b1, acc[1][1], 0,0,0);
      acc[1][2] = __builtin_amdgcn_mfma_f32_16x16x32_bf16(a1, b2, acc[1][2], 0,0,0);
      acc[1][3] = __builtin_amdgcn_mfma_f32_16x16x32_bf16(a1, b3, acc[1][3], 0,0,0);
    }

    OT* ob = Out + o_bstride * b;
    #pragma unroll
    for (int i=0;i<2;i++)
      #pragma unroll
      for (int j=0;j<4;j++)
        #pragma unroll
        for (int r=0;r<4;r++){
          const int oo = o0 + wo + i*16 + lg*4 + r;   // C/D: row=(l>>4)*4+reg
          const int nn = n0 + wn + j*16 + lr;         //      col=l&15
          st1(ob + (long long)oo*NHW + nn, acc[i][j][r]);
        }
    __syncthreads();   // protect Wt before next o-tile restage
  }
}

// depthwise 3x3, SAME zero-pad; 4 px/thread; fused sumsq (for L2 norm) for ch<384
__global__ __launch_bounds__(256) void dwconv(const unsigned short* __restrict__ pw,
    const float* __restrict__ wdw, unsigned short* __restrict__ outp,
    float* __restrict__ sumsq)
{
  const int b  = blockIdx.z;
  const int ch = blockIdx.y;
  const int t  = threadIdx.x;
  const int y  = blockIdx.x * 8 + (t >> 5);
  const int x0 = (t & 31) * 4;
  const unsigned short* base = pw + (((long long)b*NO + ch) << 14);
  float w[9];
  #pragma unroll
  for (int i=0;i<9;i++) w[i] = wdw[ch*9 + i];

  float acc0=0.f, acc1=0.f, acc2=0.f, acc3=0.f;
  #pragma unroll
  for (int dy=-1; dy<=1; dy++){
    const int yy = y + dy;
    if (yy < 0 || yy > 127) continue;
    const unsigned short* rp = base + (yy << 7);
    ushort4 v = *(const ushort4*)(rp + x0);
    const float a0 = bf2f(v.x), a1 = bf2f(v.y), a2 = bf2f(v.z), a3 = bf2f(v.w);
    const float aL = (x0 > 0)   ? bf2f(rp[x0-1]) : 0.f;
    const float aR = (x0 < 124) ? bf2f(rp[x0+4]) : 0.f;
    const float w0 = w[(dy+1)*3], w1 = w[(dy+1)*3+1], w2 = w[(dy+1)*3+2];
    acc0 += w0*aL + w1*a0 + w2*a1;
    acc1 += w0*a0 + w1*a1 + w2*a2;
    acc2 += w0*a1 + w1*a2 + w2*a3;
    acc3 += w0*a2 + w1*a3 + w2*aR;
  }
  const unsigned short r0=f2bf(acc0), r1=f2bf(acc1), r2=f2bf(acc2), r3=f2bf(acc3);
  *(ushort4*)(outp + (((long long)b*NO + ch) << 14) + (y << 7) + x0) = make_ushort4(r0,r1,r2,r3);

  if (ch < 384){
    const float f0=bf2f(r0), f1=bf2f(r1), f2v=bf2f(r2), f3=bf2f(r3);
    float s = f0*f0 + f1*f1 + f2v*f2v + f3*f3;
    #pragma unroll
    for (int off=32; off; off>>=1) s += __shfl_down(s, off);
    __shared__ float red[4];
    if ((t & 63) == 0) red[t >> 6] = s;
    __syncthreads();
    if (t == 0) atomicAdd(&sumsq[b*384 + ch], red[0]+red[1]+red[2]+red[3]);
  }
}

// raw q.k^T dots via MFMA straight from global; n-split x16 into partials
__global__ __launch_bounds__(256) void qkdots(const unsigned short* __restrict__ dw,
                                              float* __restrict__ partial)
{
  const int bh = blockIdx.x, ns = blockIdx.y;
  const int b = bh / 6, h = bh - b*6;
  const int t = threadIdx.x, w = t >> 6, l = t & 63, lr = l & 15, lg = l >> 4;
  const unsigned short* qb = dw + ((long long)b*NO + h*32) * NHW;
  const unsigned short* kb = dw + ((long long)b*NO + 192 + h*32) * NHW;
  const int nb = ns*1024 + w*256;
  f32x4 acc00 = {0.f,0.f,0.f,0.f}, acc01 = {0.f,0.f,0.f,0.f};
  f32x4 acc10 = {0.f,0.f,0.f,0.f}, acc11 = {0.f,0.f,0.f,0.f};
  #pragma unroll
  for (int kk=0; kk<8; kk++){
    const int n = nb + kk*32 + lg*8;
    bf16x8 a0 = *(const bf16x8*)(qb + (long long)(     lr)*NHW + n);
    bf16x8 a1 = *(const bf16x8*)(qb + (long long)(16 + lr)*NHW + n);
    bf16x8 b0 = *(const bf16x8*)(kb + (long long)(     lr)*NHW + n);
    bf16x8 b1 = *(const bf16x8*)(kb + (long long)(16 + lr)*NHW + n);
    acc00 = __builtin_amdgcn_mfma_f32_16x16x32_bf16(a0, b0, acc00, 0,0,0);
    acc01 = __builtin_amdgcn_mfma_f32_16x16x32_bf16(a0, b1, acc01, 0,0,0);
    acc10 = __builtin_amdgcn_mfma_f32_16x16x32_bf16(a1, b0, acc10, 0,0,0);
    acc11 = __builtin_amdgcn_mfma_f32_16x16x32_bf16(a1, b1, acc11, 0,0,0);
  }
  __shared__ float pl[4][32][32];
  #pragma unroll
  for (int r=0;r<4;r++){
    pl[w][ 0 + lg*4 + r][ 0 + lr] = acc00[r];
    pl[w][ 0 + lg*4 + r][16 + lr] = acc01[r];
    pl[w][16 + lg*4 + r][ 0 + lr] = acc10[r];
    pl[w][16 + lg*4 + r][16 + lr] = acc11[r];
  }
  __syncthreads();
  for (int e=t; e<1024; e+=256){
    const int r = e >> 5, c = e & 31;
    partial[((long long)bh*16 + ns)*1024 + e] = pl[0][r][c] + pl[1][r][c] + pl[2][r][c] + pl[3][r][c];
  }
}

__global__ __launch_bounds__(256) void softmaxk(const float* __restrict__ partial,
    const float* __restrict__ sumsq, const float* __restrict__ temp,
    float* __restrict__ attn)
{
  const int bh = blockIdx.x, b = bh / 6, h = bh - b*6;
  const int t = threadIdx.x;
  __shared__ float L[32][33];
  for (int e=t; e<1024; e+=256){
    const int c = e >> 5, d = e & 31;
    float s = 0.f;
    #pragma unroll
    for (int i=0;i<16;i++) s += partial[((long long)bh*16 + i)*1024 + e];
    const float nq = fmaxf(sqrtf(sumsq[b*384 + h*32 + c]),        1e-12f);
    const float nk = fmaxf(sqrtf(sumsq[b*384 + 192 + h*32 + d]),  1e-12f);
    L[c][d] = s / (nq * nk) * temp[h];
  }
  __syncthreads();
  if (t < 32){
    float m = -1e30f;
    #pragma unroll
    for (int d=0; d<32; d++) m = fmaxf(m, L[t][d]);
    float e[32]; float sum = 0.f;
    #pragma unroll
    for (int d=0; d<32; d++){ e[d] = expf(L[t][d] - m); sum += e[d]; }
    const float inv = 1.f / sum;
    #pragma unroll
    for (int d=0; d<32; d++) attn[(long long)bh*1024 + t*32 + d] = e[d] * inv;
  }
}

// Mcomb[b][o][h*32+d] = sum_c proj[o][h*32+c] * attn[b][h][c][d]
__global__ void mcombk(const float* __restrict__ proj, const float* __restrict__ attn,
                       unsigned short* __restrict__ mc)
{
  const int b = blockIdx.x, o = blockIdx.y, d = threadIdx.x;
  const int h = d >> 5, d32 = d & 31;
  const float* pr = proj + o*NC + h*32;
  const float* at = attn + ((long long)(b*NH + h))*1024 + d32;
  float acc = 0.f;
  #pragma unroll
  for (int c=0;c<32;c++) acc += pr[c] * at[c*32];
  mc[((long long)b*NC + o)*NC + d] = f2bf(acc);
}

extern "C" void kernel_launch(void* const* d_in, const int* in_sizes, int n_in,
                              void* d_out, int out_size, void* d_ws, size_t ws_size,
                              hipStream_t stream) {
  const float* x         = (const float*)d_in[0];
  const float* qkv_w     = (const float*)d_in[1];
  const float* qkv_dw_w  = (const float*)d_in[2];
  const float* proj_w    = (const float*)d_in[3];
  const float* temp      = (const float*)d_in[4];
  float* out = (float*)d_out;

  char* ws = (char*)d_ws;
  const size_t off_pw = 0;                                   // bf16 qkv pointwise
  const size_t off_dw = (size_t)NB*NO*NHW*2;                 // bf16 qkv depthwise (q|k|v)
  const size_t off_ss = off_dw + (size_t)NB*NO*NHW*2;        // fp32 sumsq [8][384]
  const size_t off_pp = off_ss + (size_t)NB*384*4;           // fp32 qk partials [48][16][1024]
  const size_t off_at = off_pp + (size_t)48*16*1024*4;       // fp32 attn [48][32][32]
  const size_t off_mc = off_at + (size_t)48*1024*4;          // bf16 Mcomb [8][192][192]

  unsigned short* pw     = (unsigned short*)(ws + off_pw);
  unsigned short* dwp    = (unsigned short*)(ws + off_dw);
  float*          sumsq  = (float*)(ws + off_ss);
  float*          partial= (float*)(ws + off_pp);
  float*          attn   = (float*)(ws + off_at);
  unsigned short* mcomb  = (unsigned short*)(ws + off_mc);

  hipMemsetAsync(sumsq, 0, (size_t)NB*384*sizeof(float), stream);

  // 1) qkv pointwise: pw[b][o][n] = sum_c qkv_w[o][c] x[b][c][n]
  gemm192<float, float, unsigned short><<<dim3(128,1,NB), 256, 0, stream>>>(
      qkv_w, 0LL, 9, x, (long long)NC*NHW, pw, (long long)NO*NHW);

  // 2) depthwise 3x3 + sumsq for q,k rows
  dwconv<<<dim3(16, NO, NB), 256, 0, stream>>>(pw, qkv_dw_w, dwp, sumsq);

  // 3) raw q.k^T partial dots
  qkdots<<<dim3(48,16), 256, 0, stream>>>(dwp, partial);

  // 4) normalize + temperature + softmax
  softmaxk<<<48, 256, 0, stream>>>(partial, sumsq, temp, attn);

  // 5) Mcomb = proj_w @ blockdiag(attn)
  mcombk<<<dim3(NB,192), 192, 0, stream>>>(proj_w, attn, mcomb);

  // 6) out = Mcomb @ v
  gemm192<unsigned short, unsigned short, float><<<dim3(128,1,NB), 256, 0, stream>>>(
      mcomb, (long long)NC*NC, 3, dwp + (long long)384*NHW, (long long)NO*NHW,
      out, (long long)NC*NHW);
}

// Round 2
// 426.940 us; speedup vs baseline: 1.1393x; 1.1393x over previous
//
#include <hip/hip_runtime.h>
#include <type_traits>

typedef __attribute__((ext_vector_type(8))) short bf16x8;
typedef __attribute__((ext_vector_type(4))) float f32x4;

#define NB 8
#define NC 192
#define NO 576
#define NHW 16384
#define NH 6

__device__ __forceinline__ float bf2f(unsigned short u){
  return __uint_as_float(((unsigned int)u) << 16);
}
__device__ __forceinline__ unsigned short f2bf(float f){
  unsigned int u = __float_as_uint(f);
  u += 0x7FFFu + ((u >> 16) & 1u);   // RNE
  return (unsigned short)(u >> 16);
}

__device__ __forceinline__ void st1(unsigned short* p, float v){ *p = f2bf(v); }
__device__ __forceinline__ void st1(float* p, float v){ *p = v; }

#define LSTR 200   // LDS row stride in ushorts: 400 B rows -> even 8/bank spread for b128

// convert fp32 -> bf16 (for qkv_w)
__global__ void cvt_w(const float* __restrict__ w, unsigned short* __restrict__ wb, int n4){
  const int i = blockIdx.x*256 + threadIdx.x;
  if (i < n4){
    float4 f = *(const float4*)(w + (long long)i*4);
    *(ushort4*)(wb + (long long)i*4) = make_ushort4(f2bf(f.x), f2bf(f.y), f2bf(f.z), f2bf(f.w));
  }
}

// out[b][o][n] = sum_c A[b?][o][c] * B[b][c][n],  K=192, o tiled by 64 (loop inside block).
// A: bf16, k-contiguous, read straight from global (L2-resident) -> NO A staging, NO inner barriers.
// B: staged once per block, transposed, into LDS.
template<typename BT, typename OT>
__global__ __launch_bounds__(256) void gemm192v2(
    const unsigned short* __restrict__ A, long long a_bstride, int o_tiles,
    const BT* __restrict__ Bm, long long b_bstride,
    OT* __restrict__ Out, long long o_bstride)
{
  __shared__ __align__(16) unsigned short Xt[128 * LSTR];
  const int t  = threadIdx.x;
  const int b  = blockIdx.z;
  const int n0 = blockIdx.x * 128;
  const BT* Bb = Bm + b_bstride * b;

  // stage X tile transposed: Xt[n][c]
  for (int idx = t; idx < 1536; idx += 256){
    const int n4 = (idx & 31) * 4;
    const int c  = (idx >> 5) * 4;
    if constexpr (std::is_same<BT, float>::value){
      float4 f0 = *(const float4*)(Bb + (long long)(c+0)*NHW + n0 + n4);
      float4 f1 = *(const float4*)(Bb + (long long)(c+1)*NHW + n0 + n4);
      float4 f2 = *(const float4*)(Bb + (long long)(c+2)*NHW + n0 + n4);
      float4 f3 = *(const float4*)(Bb + (long long)(c+3)*NHW + n0 + n4);
      *(ushort4*)&Xt[(n4+0)*LSTR + c] = make_ushort4(f2bf(f0.x), f2bf(f1.x), f2bf(f2.x), f2bf(f3.x));
      *(ushort4*)&Xt[(n4+1)*LSTR + c] = make_ushort4(f2bf(f0.y), f2bf(f1.y), f2bf(f2.y), f2bf(f3.y));
      *(ushort4*)&Xt[(n4+2)*LSTR + c] = make_ushort4(f2bf(f0.z), f2bf(f1.z), f2bf(f2.z), f2bf(f3.z));
      *(ushort4*)&Xt[(n4+3)*LSTR + c] = make_ushort4(f2bf(f0.w), f2bf(f1.w), f2bf(f2.w), f2bf(f3.w));
    } else {
      ushort4 u0 = *(const ushort4*)(Bb + (long long)(c+0)*NHW + n0 + n4);
      ushort4 u1 = *(const ushort4*)(Bb + (long long)(c+1)*NHW + n0 + n4);
      ushort4 u2 = *(const ushort4*)(Bb + (long long)(c+2)*NHW + n0 + n4);
      ushort4 u3 = *(const ushort4*)(Bb + (long long)(c+3)*NHW + n0 + n4);
      *(ushort4*)&Xt[(n4+0)*LSTR + c] = make_ushort4(u0.x, u1.x, u2.x, u3.x);
      *(ushort4*)&Xt[(n4+1)*LSTR + c] = make_ushort4(u0.y, u1.y, u2.y, u3.y);
      *(ushort4*)&Xt[(n4+2)*LSTR + c] = make_ushort4(u0.z, u1.z, u2.z, u3.z);
      *(ushort4*)&Xt[(n4+3)*LSTR + c] = make_ushort4(u0.w, u1.w, u2.w, u3.w);
    }
  }
  __syncthreads();

  const int l  = t & 63;
  const int w  = t >> 6;
  const int wo = (w >> 1) * 32;
  const int wn = (w & 1) * 64;
  const int lr = l & 15;
  const int lg = l >> 4;

  const unsigned short* Ab = A + a_bstride * b;
  OT* ob = Out + o_bstride * b;

  for (int ot = 0; ot < o_tiles; ++ot){
    const int o0 = ot * 64;
    const unsigned short* Aw = Ab + (long long)(o0 + wo + lr) * NC;

    f32x4 acc[2][4];
    #pragma unroll
    for (int i=0;i<2;i++)
      #pragma unroll
      for (int j=0;j<4;j++) acc[i][j] = (f32x4){0.f,0.f,0.f,0.f};

    #pragma unroll
    for (int k = 0; k < 192; k += 32){
      const int kc = k + lg*8;
      bf16x8 a0 = *(const bf16x8*)(Aw + kc);            // rows o0+wo+lr      (global, L2)
      bf16x8 a1 = *(const bf16x8*)(Aw + 16*NC + kc);    // rows o0+wo+16+lr
      bf16x8 b0 = *(const bf16x8*)&Xt[(wn +      lr)*LSTR + kc];
      bf16x8 b1 = *(const bf16x8*)&Xt[(wn + 16 + lr)*LSTR + kc];
      bf16x8 b2 = *(const bf16x8*)&Xt[(wn + 32 + lr)*LSTR + kc];
      bf16x8 b3 = *(const bf16x8*)&Xt[(wn + 48 + lr)*LSTR + kc];
      acc[0][0] = __builtin_amdgcn_mfma_f32_16x16x32_bf16(a0, b0, acc[0][0], 0,0,0);
      acc[0][1] = __builtin_amdgcn_mfma_f32_16x16x32_bf16(a0, b1, acc[0][1], 0,0,0);
      acc[0][2] = __builtin_amdgcn_mfma_f32_16x16x32_bf16(a0, b2, acc[0][2], 0,0,0);
      acc[0][3] = __builtin_amdgcn_mfma_f32_16x16x32_bf16(a0, b3, acc[0][3], 0,0,0);
      acc[1][0] = __builtin_amdgcn_mfma_f32_16x16x32_bf16(a1, b0, acc[1][0], 0,0,0);
      acc[1][1] = __builtin_amdgcn_mfma_f32_16x16x32_bf16(a1, b1, acc[1][1], 0,0,0);
      acc[1][2] = __builtin_amdgcn_mfma_f32_16x16x32_bf16(a1, b2, acc[1][2], 0,0,0);
      acc[1][3] = __builtin_amdgcn_mfma_f32_16x16x32_bf16(a1, b3, acc[1][3], 0,0,0);
    }

    #pragma unroll
    for (int i=0;i<2;i++)
      #pragma unroll
      for (int j=0;j<4;j++)
        #pragma unroll
        for (int r=0;r<4;r++){
          const int oo = o0 + wo + i*16 + lg*4 + r;   // C/D: row=(l>>4)*4+reg
          const int nn = n0 + wn + j*16 + lr;         //      col=l&15
          st1(ob + (long long)oo*NHW + nn, acc[i][j][r]);
        }
    // no barrier needed: Xt is read-only after the one-time stage
  }
}

// depthwise 3x3, SAME zero-pad; 4 px/thread; fused sumsq (for L2 norm) for ch<384
__global__ __launch_bounds__(256) void dwconv(const unsigned short* __restrict__ pw,
    const float* __restrict__ wdw, unsigned short* __restrict__ outp,
    float* __restrict__ sumsq)
{
  const int b  = blockIdx.z;
  const int ch = blockIdx.y;
  const int t  = threadIdx.x;
  const int y  = blockIdx.x * 8 + (t >> 5);
  const int x0 = (t & 31) * 4;
  const unsigned short* base = pw + (((long long)b*NO + ch) << 14);
  float w[9];
  #pragma unroll
  for (int i=0;i<9;i++) w[i] = wdw[ch*9 + i];

  float acc0=0.f, acc1=0.f, acc2=0.f, acc3=0.f;
  #pragma unroll
  for (int dy=-1; dy<=1; dy++){
    const int yy = y + dy;
    if (yy < 0 || yy > 127) continue;
    const unsigned short* rp = base + (yy << 7);
    ushort4 v = *(const ushort4*)(rp + x0);
    const float a0 = bf2f(v.x), a1 = bf2f(v.y), a2 = bf2f(v.z), a3 = bf2f(v.w);
    const float aL = (x0 > 0)   ? bf2f(rp[x0-1]) : 0.f;
    const float aR = (x0 < 124) ? bf2f(rp[x0+4]) : 0.f;
    const float w0 = w[(dy+1)*3], w1 = w[(dy+1)*3+1], w2 = w[(dy+1)*3+2];
    acc0 += w0*aL + w1*a0 + w2*a1;
    acc1 += w0*a0 + w1*a1 + w2*a2;
    acc2 += w0*a1 + w1*a2 + w2*a3;
    acc3 += w0*a2 + w1*a3 + w2*aR;
  }
  const unsigned short r0=f2bf(acc0), r1=f2bf(acc1), r2=f2bf(acc2), r3=f2bf(acc3);
  *(ushort4*)(outp + (((long long)b*NO + ch) << 14) + (y << 7) + x0) = make_ushort4(r0,r1,r2,r3);

  if (ch < 384){
    const float f0=bf2f(r0), f1=bf2f(r1), f2v=bf2f(r2), f3=bf2f(r3);
    float s = f0*f0 + f1*f1 + f2v*f2v + f3*f3;
    #pragma unroll
    for (int off=32; off; off>>=1) s += __shfl_down(s, off);
    __shared__ float red[4];
    if ((t & 63) == 0) red[t >> 6] = s;
    __syncthreads();
    if (t == 0) atomicAdd(&sumsq[b*384 + ch], red[0]+red[1]+red[2]+red[3]);
  }
}

// raw q.k^T dots via MFMA straight from global; n-split x16 into partials
__global__ __launch_bounds__(256) void qkdots(const unsigned short* __restrict__ dw,
                                              float* __restrict__ partial)
{
  const int bh = blockIdx.x, ns = blockIdx.y;
  const int b = bh / 6, h = bh - b*6;
  const int t = threadIdx.x, w = t >> 6, l = t & 63, lr = l & 15, lg = l >> 4;
  const unsigned short* qb = dw + ((long long)b*NO + h*32) * NHW;
  const unsigned short* kb = dw + ((long long)b*NO + 192 + h*32) * NHW;
  const int nb = ns*1024 + w*256;
  f32x4 acc00 = {0.f,0.f,0.f,0.f}, acc01 = {0.f,0.f,0.f,0.f};
  f32x4 acc10 = {0.f,0.f,0.f,0.f}, acc11 = {0.f,0.f,0.f,0.f};
  #pragma unroll
  for (int kk=0; kk<8; kk++){
    const int n = nb + kk*32 + lg*8;
    bf16x8 a0 = *(const bf16x8*)(qb + (long long)(     lr)*NHW + n);
    bf16x8 a1 = *(const bf16x8*)(qb + (long long)(16 + lr)*NHW + n);
    bf16x8 b0 = *(const bf16x8*)(kb + (long long)(     lr)*NHW + n);
    bf16x8 b1 = *(const bf16x8*)(kb + (long long)(16 + lr)*NHW + n);
    acc00 = __builtin_amdgcn_mfma_f32_16x16x32_bf16(a0, b0, acc00, 0,0,0);
    acc01 = __builtin_amdgcn_mfma_f32_16x16x32_bf16(a0, b1, acc01, 0,0,0);
    acc10 = __builtin_amdgcn_mfma_f32_16x16x32_bf16(a1, b0, acc10, 0,0,0);
    acc11 = __builtin_amdgcn_mfma_f32_16x16x32_bf16(a1, b1, acc11, 0,0,0);
  }
  __shared__ float pl[4][32][32];
  #pragma unroll
  for (int r=0;r<4;r++){
    pl[w][ 0 + lg*4 + r][ 0 + lr] = acc00[r];
    pl[w][ 0 + lg*4 + r][16 + lr] = acc01[r];
    pl[w][16 + lg*4 + r][ 0 + lr] = acc10[r];
    pl[w][16 + lg*4 + r][16 + lr] = acc11[r];
  }
  __syncthreads();
  for (int e=t; e<1024; e+=256){
    const int r = e >> 5, c = e & 31;
    partial[((long long)bh*16 + ns)*1024 + e] = pl[0][r][c] + pl[1][r][c] + pl[2][r][c] + pl[3][r][c];
  }
}

__global__ __launch_bounds__(256) void softmaxk(const float* __restrict__ partial,
    const float* __restrict__ sumsq, const float* __restrict__ temp,
    float* __restrict__ attn)
{
  const int bh = blockIdx.x, b = bh / 6, h = bh - b*6;
  const int t = threadIdx.x;
  __shared__ float L[32][33];
  for (int e=t; e<1024; e+=256){
    const int c = e >> 5, d = e & 31;
    float s = 0.f;
    #pragma unroll
    for (int i=0;i<16;i++) s += partial[((long long)bh*16 + i)*1024 + e];
    const float nq = fmaxf(sqrtf(sumsq[b*384 + h*32 + c]),        1e-12f);
    const float nk = fmaxf(sqrtf(sumsq[b*384 + 192 + h*32 + d]),  1e-12f);
    L[c][d] = s / (nq * nk) * temp[h];
  }
  __syncthreads();
  if (t < 32){
    float m = -1e30f;
    #pragma unroll
    for (int d=0; d<32; d++) m = fmaxf(m, L[t][d]);
    float e[32]; float sum = 0.f;
    #pragma unroll
    for (int d=0; d<32; d++){ e[d] = expf(L[t][d] - m); sum += e[d]; }
    const float inv = 1.f / sum;
    #pragma unroll
    for (int d=0; d<32; d++) attn[(long long)bh*1024 + t*32 + d] = e[d] * inv;
  }
}

// Mcomb[b][o][h*32+d] = sum_c proj[o][h*32+c] * attn[b][h][c][d]
__global__ void mcombk(const float* __restrict__ proj, const float* __restrict__ attn,
                       unsigned short* __restrict__ mc)
{
  const int b = blockIdx.x, o = blockIdx.y, d = threadIdx.x;
  const int h = d >> 5, d32 = d & 31;
  const float* pr = proj + o*NC + h*32;
  const float* at = attn + ((long long)(b*NH + h))*1024 + d32;
  float acc = 0.f;
  #pragma unroll
  for (int c=0;c<32;c++) acc += pr[c] * at[c*32];
  mc[((long long)b*NC + o)*NC + d] = f2bf(acc);
}

extern "C" void kernel_launch(void* const* d_in, const int* in_sizes, int n_in,
                              void* d_out, int out_size, void* d_ws, size_t ws_size,
                              hipStream_t stream) {
  const float* x         = (const float*)d_in[0];
  const float* qkv_w     = (const float*)d_in[1];
  const float* qkv_dw_w  = (const float*)d_in[2];
  const float* proj_w    = (const float*)d_in[3];
  const float* temp      = (const float*)d_in[4];
  float* out = (float*)d_out;

  char* ws = (char*)d_ws;
  const size_t off_pw = 0;                                   // bf16 qkv pointwise
  const size_t off_dw = (size_t)NB*NO*NHW*2;                 // bf16 qkv depthwise (q|k|v)
  const size_t off_ss = off_dw + (size_t)NB*NO*NHW*2;        // fp32 sumsq [8][384]
  const size_t off_pp = off_ss + (size_t)NB*384*4;           // fp32 qk partials [48][16][1024]
  const size_t off_at = off_pp + (size_t)48*16*1024*4;       // fp32 attn [48][32][32]
  const size_t off_mc = off_at + (size_t)48*1024*4;          // bf16 Mcomb [8][192][192]
  const size_t off_wb = off_mc + (size_t)NB*NC*NC*2;         // bf16 qkv_w [576][192]

  unsigned short* pw     = (unsigned short*)(ws + off_pw);
  unsigned short* dwp    = (unsigned short*)(ws + off_dw);
  float*          sumsq  = (float*)(ws + off_ss);
  float*          partial= (float*)(ws + off_pp);
  float*          attn   = (float*)(ws + off_at);
  unsigned short* mcomb  = (unsigned short*)(ws + off_mc);
  unsigned short* wb     = (unsigned short*)(ws + off_wb);

  hipMemsetAsync(sumsq, 0, (size_t)NB*384*sizeof(float), stream);

  // 0) qkv_w -> bf16 (L2-resident weight for direct-from-global A fragments)
  cvt_w<<<dim3((NO*NC/4 + 255)/256), 256, 0, stream>>>(qkv_w, wb, NO*NC/4);

  // 1) qkv pointwise: pw[b][o][n] = sum_c wb[o][c] x[b][c][n]
  gemm192v2<float, unsigned short><<<dim3(128,1,NB), 256, 0, stream>>>(
      wb, 0LL, 9, x, (long long)NC*NHW, pw, (long long)NO*NHW);

  // 2) depthwise 3x3 + sumsq for q,k rows
  dwconv<<<dim3(16, NO, NB), 256, 0, stream>>>(pw, qkv_dw_w, dwp, sumsq);

  // 3) raw q.k^T partial dots
  qkdots<<<dim3(48,16), 256, 0, stream>>>(dwp, partial);

  // 4) normalize + temperature + softmax
  softmaxk<<<48, 256, 0, stream>>>(partial, sumsq, temp, attn);

  // 5) Mcomb = proj_w @ blockdiag(attn)
  mcombk<<<dim3(NB,192), 192, 0, stream>>>(proj_w, attn, mcomb);

  // 6) out = Mcomb @ v
  gemm192v2<unsigned short, float><<<dim3(128,1,NB), 256, 0, stream>>>(
      mcomb, (long long)NC*NC, 3, dwp + (long long)384*NHW, (long long)NO*NHW,
      out, (long long)NC*NHW);
}

// Round 3
// 363.261 us; speedup vs baseline: 1.3390x; 1.1753x over previous
//
#include <hip/hip_runtime.h>
#include <type_traits>

typedef __attribute__((ext_vector_type(8))) short bf16x8;
typedef __attribute__((ext_vector_type(4))) float f32x4;

#define NB 8
#define NC 192
#define NO 576
#define NHW 16384
#define NH 6

__device__ __forceinline__ float bf2f(unsigned short u){
  return __uint_as_float(((unsigned int)u) << 16);
}
__device__ __forceinline__ unsigned short f2bf(float f){
  unsigned int u = __float_as_uint(f);
  u += 0x7FFFu + ((u >> 16) & 1u);   // RNE
  return (unsigned short)(u >> 16);
}

__device__ __forceinline__ void st1(unsigned short* p, float v){ *p = f2bf(v); }
__device__ __forceinline__ void st1(float* p, float v){ *p = v; }

#define LSTR 200   // LDS row stride in ushorts: 400 B rows -> even 8/bank spread for b128

// convert fp32 -> bf16 (for qkv_w)
__global__ void cvt_w(const float* __restrict__ w, unsigned short* __restrict__ wb, int n4){
  const int i = blockIdx.x*256 + threadIdx.x;
  if (i < n4){
    float4 f = *(const float4*)(w + (long long)i*4);
    *(ushort4*)(wb + (long long)i*4) = make_ushort4(f2bf(f.x), f2bf(f.y), f2bf(f.z), f2bf(f.w));
  }
}

// out[b][o][n] = sum_c A[b?][o][c] * B[b][c][n],  K=192, o tiled by 64 (loop inside block).
// A: bf16, k-contiguous, read straight from global (L2-resident) -> NO A staging, NO inner barriers.
// B: staged once per block, transposed, into LDS.
template<typename BT, typename OT>
__global__ __launch_bounds__(256) void gemm192v2(
    const unsigned short* __restrict__ A, long long a_bstride, int o_tiles,
    const BT* __restrict__ Bm, long long b_bstride,
    OT* __restrict__ Out, long long o_bstride)
{
  __shared__ __align__(16) unsigned short Xt[128 * LSTR];
  const int t  = threadIdx.x;
  const int b  = blockIdx.z;
  const int n0 = blockIdx.x * 128;
  const BT* Bb = Bm + b_bstride * b;

  // stage X tile transposed: Xt[n][c]
  for (int idx = t; idx < 1536; idx += 256){
    const int n4 = (idx & 31) * 4;
    const int c  = (idx >> 5) * 4;
    if constexpr (std::is_same<BT, float>::value){
      float4 f0 = *(const float4*)(Bb + (long long)(c+0)*NHW + n0 + n4);
      float4 f1 = *(const float4*)(Bb + (long long)(c+1)*NHW + n0 + n4);
      float4 f2 = *(const float4*)(Bb + (long long)(c+2)*NHW + n0 + n4);
      float4 f3 = *(const float4*)(Bb + (long long)(c+3)*NHW + n0 + n4);
      *(ushort4*)&Xt[(n4+0)*LSTR + c] = make_ushort4(f2bf(f0.x), f2bf(f1.x), f2bf(f2.x), f2bf(f3.x));
      *(ushort4*)&Xt[(n4+1)*LSTR + c] = make_ushort4(f2bf(f0.y), f2bf(f1.y), f2bf(f2.y), f2bf(f3.y));
      *(ushort4*)&Xt[(n4+2)*LSTR + c] = make_ushort4(f2bf(f0.z), f2bf(f1.z), f2bf(f2.z), f2bf(f3.z));
      *(ushort4*)&Xt[(n4+3)*LSTR + c] = make_ushort4(f2bf(f0.w), f2bf(f1.w), f2bf(f2.w), f2bf(f3.w));
    } else {
      ushort4 u0 = *(const ushort4*)(Bb + (long long)(c+0)*NHW + n0 + n4);
      ushort4 u1 = *(const ushort4*)(Bb + (long long)(c+1)*NHW + n0 + n4);
      ushort4 u2 = *(const ushort4*)(Bb + (long long)(c+2)*NHW + n0 + n4);
      ushort4 u3 = *(const ushort4*)(Bb + (long long)(c+3)*NHW + n0 + n4);
      *(ushort4*)&Xt[(n4+0)*LSTR + c] = make_ushort4(u0.x, u1.x, u2.x, u3.x);
      *(ushort4*)&Xt[(n4+1)*LSTR + c] = make_ushort4(u0.y, u1.y, u2.y, u3.y);
      *(ushort4*)&Xt[(n4+2)*LSTR + c] = make_ushort4(u0.z, u1.z, u2.z, u3.z);
      *(ushort4*)&Xt[(n4+3)*LSTR + c] = make_ushort4(u0.w, u1.w, u2.w, u3.w);
    }
  }
  __syncthreads();

  const int l  = t & 63;
  const int w  = t >> 6;
  const int wo = (w >> 1) * 32;
  const int wn = (w & 1) * 64;
  const int lr = l & 15;
  const int lg = l >> 4;

  const unsigned short* Ab = A + a_bstride * b;
  OT* ob = Out + o_bstride * b;

  for (int ot = 0; ot < o_tiles; ++ot){
    const int o0 = ot * 64;
    const unsigned short* Aw = Ab + (long long)(o0 + wo + lr) * NC;

    f32x4 acc[2][4];
    #pragma unroll
    for (int i=0;i<2;i++)
      #pragma unroll
      for (int j=0;j<4;j++) acc[i][j] = (f32x4){0.f,0.f,0.f,0.f};

    #pragma unroll
    for (int k = 0; k < 192; k += 32){
      const int kc = k + lg*8;
      bf16x8 a0 = *(const bf16x8*)(Aw + kc);            // rows o0+wo+lr      (global, L2)
      bf16x8 a1 = *(const bf16x8*)(Aw + 16*NC + kc);    // rows o0+wo+16+lr
      bf16x8 b0 = *(const bf16x8*)&Xt[(wn +      lr)*LSTR + kc];
      bf16x8 b1 = *(const bf16x8*)&Xt[(wn + 16 + lr)*LSTR + kc];
      bf16x8 b2 = *(const bf16x8*)&Xt[(wn + 32 + lr)*LSTR + kc];
      bf16x8 b3 = *(const bf16x8*)&Xt[(wn + 48 + lr)*LSTR + kc];
      acc[0][0] = __builtin_amdgcn_mfma_f32_16x16x32_bf16(a0, b0, acc[0][0], 0,0,0);
      acc[0][1] = __builtin_amdgcn_mfma_f32_16x16x32_bf16(a0, b1, acc[0][1], 0,0,0);
      acc[0][2] = __builtin_amdgcn_mfma_f32_16x16x32_bf16(a0, b2, acc[0][2], 0,0,0);
      acc[0][3] = __builtin_amdgcn_mfma_f32_16x16x32_bf16(a0, b3, acc[0][3], 0,0,0);
      acc[1][0] = __builtin_amdgcn_mfma_f32_16x16x32_bf16(a1, b0, acc[1][0], 0,0,0);
      acc[1][1] = __builtin_amdgcn_mfma_f32_16x16x32_bf16(a1, b1, acc[1][1], 0,0,0);
      acc[1][2] = __builtin_amdgcn_mfma_f32_16x16x32_bf16(a1, b2, acc[1][2], 0,0,0);
      acc[1][3] = __builtin_amdgcn_mfma_f32_16x16x32_bf16(a1, b3, acc[1][3], 0,0,0);
    }

    #pragma unroll
    for (int i=0;i<2;i++)
      #pragma unroll
      for (int j=0;j<4;j++)
        #pragma unroll
        for (int r=0;r<4;r++){
          const int oo = o0 + wo + i*16 + lg*4 + r;   // C/D: row=(l>>4)*4+reg
          const int nn = n0 + wn + j*16 + lr;         //      col=l&15
          st1(ob + (long long)oo*NHW + nn, acc[i][j][r]);
        }
    // no barrier needed: Xt is read-only after the one-time stage
  }
}

// depthwise 3x3, SAME zero-pad. One block per (b,ch) image; thread owns an
// 8-wide column strip x 8 rows; rolling 3-row accumulators, halo via __shfl.
__global__ __launch_bounds__(256) void dwconv2(const unsigned short* __restrict__ pw,
    const float* __restrict__ wdw, unsigned short* __restrict__ outp,
    float* __restrict__ sumsq)
{
  const int ch = blockIdx.x;
  const int b  = blockIdx.y;
  const int t  = threadIdx.x;
  const int lane  = t & 63;
  const int strip = t & 15;        // column strip 0..15  (x0 = strip*8)
  const int y0    = (t >> 4) * 8;  // 16 row-groups x 8 rows = 128
  const int x0    = strip * 8;

  const long long choff = ((long long)b*NO + ch) << 14;
  const unsigned short* base = pw + choff;
  unsigned short* ob = outp + choff;

  float w[9];
  #pragma unroll
  for (int i=0;i<9;i++) w[i] = wdw[ch*9 + i];

  float a0[8], a1[8], a2[8];
  #pragma unroll
  for (int i=0;i<8;i++){ a0[i]=0.f; a1[i]=0.f; a2[i]=0.f; }
  float ss = 0.f;

  #pragma unroll
  for (int r = 0; r < 10; ++r){
    const int yy = y0 - 1 + r;
    float f[8];
    if (yy >= 0 && yy <= 127){
      uint4 u = *(const uint4*)(base + (yy << 7) + x0);
      f[0]=bf2f((unsigned short)(u.x&0xffff)); f[1]=bf2f((unsigned short)(u.x>>16));
      f[2]=bf2f((unsigned short)(u.y&0xffff)); f[3]=bf2f((unsigned short)(u.y>>16));
      f[4]=bf2f((unsigned short)(u.z&0xffff)); f[5]=bf2f((unsigned short)(u.z>>16));
      f[6]=bf2f((unsigned short)(u.w&0xffff)); f[7]=bf2f((unsigned short)(u.w>>16));
    } else {
      #pragma unroll
      for (int i=0;i<8;i++) f[i]=0.f;
    }
    // column halos from neighbor strips (same row-group => same yy)
    float lf = __shfl(f[7], lane - 1, 64);
    float rf = __shfl(f[0], lane + 1, 64);
    if (strip == 0)  lf = 0.f;
    if (strip == 15) rf = 0.f;

    #pragma unroll
    for (int i=0;i<8;i++){
      const float hL = (i==0) ? lf : f[i-1];
      const float hC = f[i];
      const float hR = (i==7) ? rf : f[i+1];
      a0[i] += w[6]*hL + w[7]*hC + w[8]*hR;   // -> output row yy-1 (dy=+1)
      a1[i] += w[3]*hL + w[4]*hC + w[5]*hR;   // -> output row yy   (dy= 0)
      a2[i] += w[0]*hL + w[1]*hC + w[2]*hR;   // -> output row yy+1 (dy=-1)
    }

    if (r >= 2){
      const int yo = y0 + r - 2;   // completed output row
      uint4 o;
      o.x = (unsigned int)f2bf(a0[0]) | ((unsigned int)f2bf(a0[1]) << 16);
      o.y = (unsigned int)f2bf(a0[2]) | ((unsigned int)f2bf(a0[3]) << 16);
      o.z = (unsigned int)f2bf(a0[4]) | ((unsigned int)f2bf(a0[5]) << 16);
      o.w = (unsigned int)f2bf(a0[6]) | ((unsigned int)f2bf(a0[7]) << 16);
      *(uint4*)(ob + (yo << 7) + x0) = o;
      #pragma unroll
      for (int i=0;i<8;i++) ss += a0[i]*a0[i];
    }
    // rotate
    #pragma unroll
    for (int i=0;i<8;i++){ a0[i]=a1[i]; a1[i]=a2[i]; a2[i]=0.f; }
  }

  if (ch < 384){
    #pragma unroll
    for (int off=32; off; off>>=1) ss += __shfl_down(ss, off);
    if (lane == 0) atomicAdd(&sumsq[b*384 + ch], ss);
  }
}

// raw q.k^T dots via MFMA straight from global; n-split x16 into partials
__global__ __launch_bounds__(256) void qkdots(const unsigned short* __restrict__ dw,
                                              float* __restrict__ partial)
{
  const int bh = blockIdx.x, ns = blockIdx.y;
  const int b = bh / 6, h = bh - b*6;
  const int t = threadIdx.x, w = t >> 6, l = t & 63, lr = l & 15, lg = l >> 4;
  const unsigned short* qb = dw + ((long long)b*NO + h*32) * NHW;
  const unsigned short* kb = dw + ((long long)b*NO + 192 + h*32) * NHW;
  const int nb = ns*1024 + w*256;
  f32x4 acc00 = {0.f,0.f,0.f,0.f}, acc01 = {0.f,0.f,0.f,0.f};
  f32x4 acc10 = {0.f,0.f,0.f,0.f}, acc11 = {0.f,0.f,0.f,0.f};
  #pragma unroll
  for (int kk=0; kk<8; kk++){
    const int n = nb + kk*32 + lg*8;
    bf16x8 a0 = *(const bf16x8*)(qb + (long long)(     lr)*NHW + n);
    bf16x8 a1 = *(const bf16x8*)(qb + (long long)(16 + lr)*NHW + n);
    bf16x8 b0 = *(const bf16x8*)(kb + (long long)(     lr)*NHW + n);
    bf16x8 b1 = *(const bf16x8*)(kb + (long long)(16 + lr)*NHW + n);
    acc00 = __builtin_amdgcn_mfma_f32_16x16x32_bf16(a0, b0, acc00, 0,0,0);
    acc01 = __builtin_amdgcn_mfma_f32_16x16x32_bf16(a0, b1, acc01, 0,0,0);
    acc10 = __builtin_amdgcn_mfma_f32_16x16x32_bf16(a1, b0, acc10, 0,0,0);
    acc11 = __builtin_amdgcn_mfma_f32_16x16x32_bf16(a1, b1, acc11, 0,0,0);
  }
  __shared__ float pl[4][32][32];
  #pragma unroll
  for (int r=0;r<4;r++){
    pl[w][ 0 + lg*4 + r][ 0 + lr] = acc00[r];
    pl[w][ 0 + lg*4 + r][16 + lr] = acc01[r];
    pl[w][16 + lg*4 + r][ 0 + lr] = acc10[r];
    pl[w][16 + lg*4 + r][16 + lr] = acc11[r];
  }
  __syncthreads();
  for (int e=t; e<1024; e+=256){
    const int r = e >> 5, c = e & 31;
    partial[((long long)bh*16 + ns)*1024 + e] = pl[0][r][c] + pl[1][r][c] + pl[2][r][c] + pl[3][r][c];
  }
}

__global__ __launch_bounds__(256) void softmaxk(const float* __restrict__ partial,
    const float* __restrict__ sumsq, const float* __restrict__ temp,
    float* __restrict__ attn)
{
  const int bh = blockIdx.x, b = bh / 6, h = bh - b*6;
  const int t = threadIdx.x;
  __shared__ float L[32][33];
  for (int e=t; e<1024; e+=256){
    const int c = e >> 5, d = e & 31;
    float s = 0.f;
    #pragma unroll
    for (int i=0;i<16;i++) s += partial[((long long)bh*16 + i)*1024 + e];
    const float nq = fmaxf(sqrtf(sumsq[b*384 + h*32 + c]),        1e-12f);
    const float nk = fmaxf(sqrtf(sumsq[b*384 + 192 + h*32 + d]),  1e-12f);
    L[c][d] = s / (nq * nk) * temp[h];
  }
  __syncthreads();
  if (t < 32){
    float m = -1e30f;
    #pragma unroll
    for (int d=0; d<32; d++) m = fmaxf(m, L[t][d]);
    float e[32]; float sum = 0.f;
    #pragma unroll
    for (int d=0; d<32; d++){ e[d] = expf(L[t][d] - m); sum += e[d]; }
    const float inv = 1.f / sum;
    #pragma unroll
    for (int d=0; d<32; d++) attn[(long long)bh*1024 + t*32 + d] = e[d] * inv;
  }
}

// Mcomb[b][o][h*32+d] = sum_c proj[o][h*32+c] * attn[b][h][c][d]
__global__ void mcombk(const float* __restrict__ proj, const float* __restrict__ attn,
                       unsigned short* __restrict__ mc)
{
  const int b = blockIdx.x, o = blockIdx.y, d = threadIdx.x;
  const int h = d >> 5, d32 = d & 31;
  const float* pr = proj + o*NC + h*32;
  const float* at = attn + ((long long)(b*NH + h))*1024 + d32;
  float acc = 0.f;
  #pragma unroll
  for (int c=0;c<32;c++) acc += pr[c] * at[c*32];
  mc[((long long)b*NC + o)*NC + d] = f2bf(acc);
}

extern "C" void kernel_launch(void* const* d_in, const int* in_sizes, int n_in,
                              void* d_out, int out_size, void* d_ws, size_t ws_size,
                              hipStream_t stream) {
  const float* x         = (const float*)d_in[0];
  const float* qkv_w     = (const float*)d_in[1];
  const float* qkv_dw_w  = (const float*)d_in[2];
  const float* proj_w    = (const float*)d_in[3];
  const float* temp      = (const float*)d_in[4];
  float* out = (float*)d_out;

  char* ws = (char*)d_ws;
  const size_t off_pw = 0;                                   // bf16 qkv pointwise
  const size_t off_dw = (size_t)NB*NO*NHW*2;                 // bf16 qkv depthwise (q|k|v)
  const size_t off_ss = off_dw + (size_t)NB*NO*NHW*2;        // fp32 sumsq [8][384]
  const size_t off_pp = off_ss + (size_t)NB*384*4;           // fp32 qk partials [48][16][1024]
  const size_t off_at = off_pp + (size_t)48*16*1024*4;       // fp32 attn [48][32][32]
  const size_t off_mc = off_at + (size_t)48*1024*4;          // bf16 Mcomb [8][192][192]
  const size_t off_wb = off_mc + (size_t)NB*NC*NC*2;         // bf16 qkv_w [576][192]

  unsigned short* pw     = (unsigned short*)(ws + off_pw);
  unsigned short* dwp    = (unsigned short*)(ws + off_dw);
  float*          sumsq  = (float*)(ws + off_ss);
  float*          partial= (float*)(ws + off_pp);
  float*          attn   = (float*)(ws + off_at);
  unsigned short* mcomb  = (unsigned short*)(ws + off_mc);
  unsigned short* wb     = (unsigned short*)(ws + off_wb);

  hipMemsetAsync(sumsq, 0, (size_t)NB*384*sizeof(float), stream);

  // 0) qkv_w -> bf16 (L2-resident weight for direct-from-global A fragments)
  cvt_w<<<dim3((NO*NC/4 + 255)/256), 256, 0, stream>>>(qkv_w, wb, NO*NC/4);

  // 1) qkv pointwise: pw[b][o][n] = sum_c wb[o][c] x[b][c][n]
  gemm192v2<float, unsigned short><<<dim3(128,1,NB), 256, 0, stream>>>(
      wb, 0LL, 9, x, (long long)NC*NHW, pw, (long long)NO*NHW);

  // 2) depthwise 3x3 + sumsq for q,k rows
  dwconv2<<<dim3(NO, NB), 256, 0, stream>>>(pw, qkv_dw_w, dwp, sumsq);

  // 3) raw q.k^T partial dots
  qkdots<<<dim3(48,16), 256, 0, stream>>>(dwp, partial);

  // 4) normalize + temperature + softmax
  softmaxk<<<48, 256, 0, stream>>>(partial, sumsq, temp, attn);

  // 5) Mcomb = proj_w @ blockdiag(attn)
  mcombk<<<dim3(NB,192), 192, 0, stream>>>(proj_w, attn, mcomb);

  // 6) out = Mcomb @ v
  gemm192v2<unsigned short, float><<<dim3(128,1,NB), 256, 0, stream>>>(
      mcomb, (long long)NC*NC, 3, dwp + (long long)384*NHW, (long long)NO*NHW,
      out, (long long)NC*NHW);
}